// Round 2
// baseline (341.506 us; speedup 1.0000x reference)
//
#include <hip/hip_runtime.h>

typedef unsigned int u32;
typedef unsigned long long u64;
typedef unsigned short u16;
typedef float v2f __attribute__((ext_vector_type(2)));

#define DEV __device__ __forceinline__

// ---------- helpers ----------
DEV u16 f2bf(float x) {                      // fp32 -> bf16 RNE
  u32 u = __float_as_uint(x);
  u32 r = u + 0x7fffu + ((u >> 16) & 1u);
  return (u16)(r >> 16);
}
DEV float bflo(u32 d) { return __uint_as_float(d << 16); }
DEV float bfhi(u32 d) { return __uint_as_float(d & 0xffff0000u); }
DEV u64 sortable64(double f) {               // monotonic f64 -> u64
  long long b = __double_as_longlong(f);
  return (u64)b ^ (u64)((b >> 63) | (long long)0x8000000000000000ll);
}
// fp64 exact-selection distance (float products are exact in f64)
DEV double ddist(double qx, double qy, double qz, double qd2,
                 float mxf, float myf, float mzf) {
  double cx = (double)mxf, cy = (double)myf, cz = (double)mzf;
  double cd2 = cx * cx + cy * cy + cz * cz;
  double dot = cx * qx + cy * qy + cz * qz;
  return (qd2 + cd2) - 2.0 * dot;
}
DEV float fmin3f(float a, float b, float c) {   // hope: v_min3_f32
  return __builtin_fminf(__builtin_fminf(a, b), c);
}
DEV v2f vfma2(v2f a, v2f b, v2f c) { return __builtin_elementwise_fma(a, b, c); }

#define NB 2
#define NN 8192
#define NC 128
#define KK 21
// screening metric: st = cd2 - 2*dot (qd2 dropped — per-query constant shift).
// fp32 error vs fp64 <= ~2e-4 on these operand scales; MARGIN covers it so the
// fp64 top-21 set provably survives fp32 screening.
#define MARGIN 1e-3f

// ---------- K0: fold BN into weights ----------
__global__ __launch_bounds__(256) void k_prep(
    const float* __restrict__ Wf, const float* __restrict__ gf, const float* __restrict__ bf_,
    const float* __restrict__ mf, const float* __restrict__ vf,
    const float* __restrict__ Wg, const float* __restrict__ gg, const float* __restrict__ bg,
    const float* __restrict__ mg, const float* __restrict__ vg,
    u16* __restrict__ Wt, float* __restrict__ beta_f,
    float* __restrict__ Wgu, float* __restrict__ Wgv, float* __restrict__ beta_g) {
  int g = blockIdx.x * 256 + threadIdx.x;     // 0..32767
  int c = g >> 8, o = g & 255;
  float val;
  if (o < 128) {
    float inv = gf[o] / sqrtf(vf[o] + 1e-5f);
    val = inv * (Wf[o * 256 + c] - Wf[o * 256 + c + 128]);
  } else {
    int o2 = o - 128;
    float inv = gf[o2] / sqrtf(vf[o2] + 1e-5f);
    val = inv * Wf[o2 * 256 + c + 128];
  }
  Wt[c * 256 + o] = f2bf(val);
  if (g < 128) {
    float inv = gf[g] / sqrtf(vf[g] + 1e-5f);
    beta_f[g] = bf_[g] - mf[g] * inv;
  } else if (g < 256) {
    int oo = g - 128;
    float invg = gg[oo] / sqrtf(vg[oo] + 1e-5f);
#pragma unroll
    for (int d = 0; d < 3; ++d) {
      Wgu[oo * 3 + d] = invg * (Wg[oo * 6 + d] - Wg[oo * 6 + 3 + d]);
      Wgv[oo * 3 + d] = invg * Wg[oo * 6 + 3 + d];
    }
    beta_g[oo] = bg[oo] - mg[oo] * invg;
  }
}

// ---------- K1geo ----------
__global__ __launch_bounds__(256) void k_geo(
    const float* __restrict__ xyz, const float* __restrict__ Wgu, const float* __restrict__ Wgv,
    const float* __restrict__ beta_g, u32* __restrict__ ucat, u32* __restrict__ vcat) {
  int g = blockIdx.x * 256 + threadIdx.x;     // < 16384*64
  int p = g >> 6, oc = g & 63;
  const float* xp = xyz + p * 3;
  float X = xp[0], Y = xp[1], Z = xp[2];
  u32 du = 0, dv = 0;
#pragma unroll
  for (int h = 0; h < 2; ++h) {
    int o = oc * 2 + h;
    float ug = X * Wgu[o * 3] + Y * Wgu[o * 3 + 1] + Z * Wgu[o * 3 + 2] + beta_g[o];
    float vv = X * Wgv[o * 3] + Y * Wgv[o * 3 + 1] + Z * Wgv[o * 3 + 2];
    du |= (u32)f2bf(ug) << (16 * h);
    dv |= (u32)f2bf(vv) << (16 * h);
  }
  ucat[p * 128 + oc] = du;
  vcat[p * 128 + oc] = dv;
}

// ---------- K1f: feat branch GEMM ----------
__global__ __launch_bounds__(256) void k_feat(
    const float* __restrict__ f, const u32* __restrict__ Wt32, const float* __restrict__ beta_f,
    u32* __restrict__ ucat, u32* __restrict__ vcat) {
  __shared__ u32 sW[128 * 128];
  __shared__ float sF[128][68];

  const int t = threadIdx.x;
  const int b = blockIdx.x >> 7;
  const int n0 = (blockIdx.x & 127) << 6;
  const int boff = b * (NC * NN);

#pragma unroll
  for (int k = 0; k < 64; ++k) sW[t + (k << 8)] = Wt32[t + (k << 8)];
#pragma unroll
  for (int k = 0; k < 32; ++k) {
    int i = t + (k << 8);
    int c = i >> 6, col = i & 63;
    sF[c][col] = f[boff + c * NN + n0 + col];
  }
  __syncthreads();

  const int w = t >> 6, lane = t & 63;
  const int og = lane >> 3, pg = lane & 7;
  const int o0 = w * 64 + og * 8;
  const int p0 = pg * 8;

  float acc[8][8];
#pragma unroll
  for (int a = 0; a < 8; ++a)
#pragma unroll
    for (int p = 0; p < 8; ++p) acc[a][p] = 0.0f;

  for (int c = 0; c < 128; ++c) {
    float4 fa = *(const float4*)&sF[c][p0];
    float4 fb = *(const float4*)&sF[c][p0 + 4];
    uint4 wr = *(const uint4*)&sW[c * 128 + (o0 >> 1)];
    float wv[8] = {bflo(wr.x), bfhi(wr.x), bflo(wr.y), bfhi(wr.y),
                   bflo(wr.z), bfhi(wr.z), bflo(wr.w), bfhi(wr.w)};
    float fv[8] = {fa.x, fa.y, fa.z, fa.w, fb.x, fb.y, fb.z, fb.w};
#pragma unroll
    for (int a = 0; a < 8; ++a)
#pragma unroll
      for (int p = 0; p < 8; ++p) acc[a][p] = __builtin_fmaf(wv[a], fv[p], acc[a][p]);
  }

  const int ochan = o0 & 127;
  const bool is_u = (o0 < 128);
  float bet[8];
#pragma unroll
  for (int a = 0; a < 8; ++a) bet[a] = is_u ? beta_f[ochan + a] : 0.0f;
  u32* dstbase = is_u ? ucat : vcat;
#pragma unroll
  for (int p = 0; p < 8; ++p) {
    int pt = (b << 13) + n0 + p0 + p;
    u32 d0 = (u32)f2bf(acc[0][p] + bet[0]) | ((u32)f2bf(acc[1][p] + bet[1]) << 16);
    u32 d1 = (u32)f2bf(acc[2][p] + bet[2]) | ((u32)f2bf(acc[3][p] + bet[3]) << 16);
    u32 d2 = (u32)f2bf(acc[4][p] + bet[4]) | ((u32)f2bf(acc[5][p] + bet[5]) << 16);
    u32 d3 = (u32)f2bf(acc[6][p] + bet[6]) | ((u32)f2bf(acc[7][p] + bet[7]) << 16);
    *(uint4*)&dstbase[pt * 128 + 64 + (ochan >> 1)] = make_uint4(d0, d1, d2, d3);
  }
}

// ---------- K2: exact KNN (k=21) ----------
// Latency/occupancy-bound before (16 waves/CU, VALUBusy<60%). Now: 2048 blocks
// (8 q/block), each wave evaluates all 8 queries on a quarter of candidates ->
// 32 waves/CU (8/SIMD); barrier bubbles overlap across 8 resident blocks/CU.
// SoA x/y/z/d2 tile (1024 cand, 16KB): one ds_read_b128 = 4 candidates with
// components register-adjacent for packed v2f fma; d2 staged once so pass A/B
// use identical values. Threshold: per-quarter 21st-of-64-lane-minima bound,
// min'd over quarters (valid upper bound on global d21 by witness argument).
__global__ __launch_bounds__(256, 8) void k_knn(const float* __restrict__ xyz,
                                                int* __restrict__ knn) {
  __shared__ float sx[1024], sy[1024], sz[1024], sd[1024];   // 16 KB SoA tile
  __shared__ u16 ssurv[8][128];                              // 2 KB
  __shared__ u32 scnt[8];
  __shared__ float sthr[4][8];

  const int t = threadIdx.x;
  const int blk = blockIdx.x;                 // 0..2047
  const int b = blk >> 10;                    // 1024 blocks per batch
  const int n0 = (blk & 1023) << 3;           // 8 queries per block
  const float* X = xyz + b * (NN * 3);

  if (t < 8) scnt[t] = 0u;

  const int w = t >> 6, lane = t & 63;
  const int ci = (w << 8) + (lane << 2);      // this lane's 4 candidates in tile

  float mx[8], my[8], mz[8], mn[8];
#pragma unroll
  for (int i = 0; i < 8; ++i) {
    int q = n0 + i;
    mx[i] = -2.0f * X[q * 3];
    my[i] = -2.0f * X[q * 3 + 1];
    mz[i] = -2.0f * X[q * 3 + 2];
    mn[i] = __builtin_inff();
  }

  // ---- pass A: per-lane running min of st = cd2 - 2*dot (this wave's quarter) ----
  for (int ct = 0; ct < 8; ++ct) {
    __syncthreads();                          // guard tile buffer reuse
    {
      const float* src = X + ct * 3072 + t * 12;
      float4 q0 = *(const float4*)(src);      // x0 y0 z0 x1
      float4 q1 = *(const float4*)(src + 4);  // y1 z1 x2 y2
      float4 q2 = *(const float4*)(src + 8);  // z2 x3 y3 z3
      int c0 = t << 2;
      *(float4*)&sx[c0] = make_float4(q0.x, q0.w, q1.z, q2.y);
      *(float4*)&sy[c0] = make_float4(q0.y, q1.x, q1.w, q2.z);
      *(float4*)&sz[c0] = make_float4(q0.z, q1.y, q2.x, q2.w);
      v2f x01 = {q0.x, q0.w}, x23 = {q1.z, q2.y};
      v2f y01 = {q0.y, q1.x}, y23 = {q1.w, q2.z};
      v2f z01 = {q0.z, q1.y}, z23 = {q2.x, q2.w};
      v2f w01 = vfma2(x01, x01, vfma2(y01, y01, z01 * z01));
      v2f w23 = vfma2(x23, x23, vfma2(y23, y23, z23 * z23));
      *(float4*)&sd[c0] = make_float4(w01.x, w01.y, w23.x, w23.y);
    }
    __syncthreads();
    float4 X4 = *(const float4*)&sx[ci];
    float4 Y4 = *(const float4*)&sy[ci];
    float4 Z4 = *(const float4*)&sz[ci];
    float4 D4 = *(const float4*)&sd[ci];
    v2f x01 = {X4.x, X4.y}, x23 = {X4.z, X4.w};
    v2f y01 = {Y4.x, Y4.y}, y23 = {Y4.z, Y4.w};
    v2f z01 = {Z4.x, Z4.y}, z23 = {Z4.z, Z4.w};
    v2f w01 = {D4.x, D4.y}, w23 = {D4.z, D4.w};
#pragma unroll
    for (int i = 0; i < 8; ++i) {
      v2f mxv = {mx[i], mx[i]}, myv = {my[i], my[i]}, mzv = {mz[i], mz[i]};
      v2f s01 = vfma2(x01, mxv, vfma2(y01, myv, vfma2(z01, mzv, w01)));
      v2f s23 = vfma2(x23, mxv, vfma2(y23, myv, vfma2(z23, mzv, w23)));
      mn[i] = fmin3f(mn[i], s01.x, s01.y);
      mn[i] = fmin3f(mn[i], s23.x, s23.y);
    }
  }

  // ---- threshold: 21st smallest of 64 disjoint-subset lane minima per quarter,
  //      then min across the four quarters ----
#pragma unroll 1
  for (int i = 0; i < 8; ++i) {
    float v = mn[i];
#pragma unroll
    for (int k = 2; k <= 64; k <<= 1) {
#pragma unroll
      for (int j = k >> 1; j > 0; j >>= 1) {
        float p = __shfl_xor(v, j);
        bool takeMin = (((lane & k) == 0) == ((lane & j) == 0));
        v = takeMin ? fminf(v, p) : fmaxf(v, p);
      }
    }
    float tw = __shfl(v, 20);
    if (lane == 0) sthr[w][i] = tw;
  }
  __syncthreads();
  float thr[8];
#pragma unroll
  for (int i = 0; i < 8; ++i)
    thr[i] = fminf(fminf(sthr[0][i], sthr[1][i]),
                   fminf(sthr[2][i], sthr[3][i])) + MARGIN;

  // ---- pass B: compact survivors (identical staged values as pass A) ----
  for (int ct = 0; ct < 8; ++ct) {
    __syncthreads();
    {
      const float* src = X + ct * 3072 + t * 12;
      float4 q0 = *(const float4*)(src);
      float4 q1 = *(const float4*)(src + 4);
      float4 q2 = *(const float4*)(src + 8);
      int c0 = t << 2;
      *(float4*)&sx[c0] = make_float4(q0.x, q0.w, q1.z, q2.y);
      *(float4*)&sy[c0] = make_float4(q0.y, q1.x, q1.w, q2.z);
      *(float4*)&sz[c0] = make_float4(q0.z, q1.y, q2.x, q2.w);
      v2f x01 = {q0.x, q0.w}, x23 = {q1.z, q2.y};
      v2f y01 = {q0.y, q1.x}, y23 = {q1.w, q2.z};
      v2f z01 = {q0.z, q1.y}, z23 = {q2.x, q2.w};
      v2f w01 = vfma2(x01, x01, vfma2(y01, y01, z01 * z01));
      v2f w23 = vfma2(x23, x23, vfma2(y23, y23, z23 * z23));
      *(float4*)&sd[c0] = make_float4(w01.x, w01.y, w23.x, w23.y);
    }
    __syncthreads();
    float4 X4 = *(const float4*)&sx[ci];
    float4 Y4 = *(const float4*)&sy[ci];
    float4 Z4 = *(const float4*)&sz[ci];
    float4 D4 = *(const float4*)&sd[ci];
    v2f x01 = {X4.x, X4.y}, x23 = {X4.z, X4.w};
    v2f y01 = {Y4.x, Y4.y}, y23 = {Y4.z, Y4.w};
    v2f z01 = {Z4.x, Z4.y}, z23 = {Z4.z, Z4.w};
    v2f w01 = {D4.x, D4.y}, w23 = {D4.z, D4.w};
    const int mbase = ct * 1024 + ci;
#pragma unroll
    for (int i = 0; i < 8; ++i) {
      v2f mxv = {mx[i], mx[i]}, myv = {my[i], my[i]}, mzv = {mz[i], mz[i]};
      v2f s01 = vfma2(x01, mxv, vfma2(y01, myv, vfma2(z01, mzv, w01)));
      v2f s23 = vfma2(x23, mxv, vfma2(y23, myv, vfma2(z23, mzv, w23)));
      float worst = fminf(fmin3f(s01.x, s01.y, s23.x), s23.y);
      if (worst <= thr[i]) {                  // rare-taken: one branch per (q,4c)
        if (s01.x <= thr[i]) {
          u32 slot = atomicAdd(&scnt[i], 1u);
          if (slot < 128u) ssurv[i][slot] = (u16)(mbase + 0);
        }
        if (s01.y <= thr[i]) {
          u32 slot = atomicAdd(&scnt[i], 1u);
          if (slot < 128u) ssurv[i][slot] = (u16)(mbase + 1);
        }
        if (s23.x <= thr[i]) {
          u32 slot = atomicAdd(&scnt[i], 1u);
          if (slot < 128u) ssurv[i][slot] = (u16)(mbase + 2);
        }
        if (s23.y <= thr[i]) {
          u32 slot = atomicAdd(&scnt[i], 1u);
          if (slot < 128u) ssurv[i][slot] = (u16)(mbase + 3);
        }
      }
    }
  }
  __syncthreads();

  // ---- selection: exact top-21 by fp64 (dist, idx); 2 queries per wave ----
#pragma unroll 1
  for (int i = 0; i < 2; ++i) {
    const int qq = (w << 1) + i;
    const int q = n0 + qq;
    double Qx = (double)X[q * 3], Qy = (double)X[q * 3 + 1], Qz = (double)X[q * 3 + 2];
    double Qd2 = Qx * Qx + Qy * Qy + Qz * Qz;
    u32 cnt = scnt[qq];
    if (cnt > 128u) cnt = 128u;
    int* outp = knn + ((b << 13) + q) * KK;

    bool v0 = ((u32)lane < cnt);
    u32 m0 = v0 ? (u32)ssurv[qq][lane] : 0u;
    double s0 = ddist(Qx, Qy, Qz, Qd2, X[m0 * 3], X[m0 * 3 + 1], X[m0 * 3 + 2]);
    // key: fp64-sortable, low 13 bits replaced by idx (lowest-index tie-break)
    u64 k0 = v0 ? ((sortable64(s0) & 0xFFFFFFFFFFFFE000ull) | (u64)m0) : ~0ull;

    if (cnt <= 64u) {
      u64 v = k0;
#pragma unroll
      for (int k = 2; k <= 64; k <<= 1) {
#pragma unroll
        for (int j = k >> 1; j > 0; j >>= 1) {
          u64 p = __shfl_xor(v, j);
          bool takeMin = (((lane & k) == 0) == ((lane & j) == 0));
          bool pl = p < v;
          u64 mnv = pl ? p : v;
          u64 mxv = pl ? v : p;
          v = takeMin ? mnv : mxv;
        }
      }
      if (lane < KK) outp[lane] = (int)(v & 8191ull);
    } else {
      bool v1 = ((u32)(lane + 64) < cnt);
      u32 m1 = v1 ? (u32)ssurv[qq][lane + 64] : 0u;
      double s1 = ddist(Qx, Qy, Qz, Qd2, X[m1 * 3], X[m1 * 3 + 1], X[m1 * 3 + 2]);
      u64 k1 = v1 ? ((sortable64(s1) & 0xFFFFFFFFFFFFE000ull) | (u64)m1) : ~0ull;
      u32 selm = 0;
      for (int r = 0; r < KK; ++r) {
        u64 mk = (k0 < k1) ? k0 : k1;
#pragma unroll
        for (int j = 32; j > 0; j >>= 1) {
          u64 p = __shfl_xor(mk, j);
          if (p < mk) mk = p;
        }
        if (k0 == mk) k0 = ~0ull;
        else if (k1 == mk) k1 = ~0ull;
        if (lane == r) selm = (u32)(mk & 8191ull);
      }
      if (lane < KK) outp[lane] = (int)selm;
    }
  }
}

// ---------- K3: gather + max + relu + transpose-write ----------
__global__ __launch_bounds__(256) void k_gather(
    const u32* __restrict__ ucat, const u32* __restrict__ vcat,
    const int* __restrict__ knn, float* __restrict__ out) {
  __shared__ float tr[64 * 258];

  const int t = threadIdx.x;
  const int b = blockIdx.x >> 7;
  const int n0 = (blockIdx.x & 127) << 6;
  const int w = t >> 6, lane = t & 63;
  const int which = w >> 1;
  const int lo = ((w & 1) << 6) | lane;

  for (int step = 0; step < 32; ++step) {
    int qq = step * 2 + which;
    int q = n0 + qq;
    const int* ip = knn + ((b << 13) + q) * KK;
    float a0 = -__builtin_inff(), a1 = -__builtin_inff();
#pragma unroll
    for (int k = 0; k < KK; ++k) {
      int p = ip[k];
      u32 d = vcat[(((b << 13) + p) << 7) + lo];
      a0 = fmaxf(a0, bflo(d));
      a1 = fmaxf(a1, bfhi(d));
    }
    u32 u = ucat[(((b << 13) + q) << 7) + lo];
    float r0 = fmaxf(bflo(u) + a0, 0.0f);
    float r1 = fmaxf(bfhi(u) + a1, 0.0f);
    *(float2*)&tr[qq * 258 + 2 * lo] = make_float2(r0, r1);
  }
  __syncthreads();

  float* ob = out + b * (256 * NN);
  for (int i = 0; i < 64; ++i) {
    int o = (w << 6) + i;
    ob[o * NN + n0 + lane] = tr[lane * 258 + o];
  }
}

// ---------- launch ----------
extern "C" void kernel_launch(void* const* d_in, const int* in_sizes, int n_in,
                              void* d_out, int out_size, void* d_ws, size_t ws_size,
                              hipStream_t stream) {
  const float* xyz = (const float*)d_in[0];
  const float* f   = (const float*)d_in[1];
  const float* Wg  = (const float*)d_in[2];
  const float* gg  = (const float*)d_in[3];
  const float* bg  = (const float*)d_in[4];
  const float* mg  = (const float*)d_in[5];
  const float* vg  = (const float*)d_in[6];
  const float* Wf  = (const float*)d_in[7];
  const float* gf  = (const float*)d_in[8];
  const float* bf_ = (const float*)d_in[9];
  const float* mf  = (const float*)d_in[10];
  const float* vf  = (const float*)d_in[11];

  char* ws = (char*)d_ws;
  u16*   Wt     = (u16*)ws;                               // 65536 B
  float* beta_f = (float*)(ws + 65536);
  float* Wgu    = (float*)(ws + 66048);
  float* Wgv    = (float*)(ws + 67584);
  float* beta_g = (float*)(ws + 69120);
  u32*   ucat   = (u32*)(ws + 69632);                     // 8 MB
  u32*   vcat   = (u32*)(ws + 69632 + 8388608);           // 8 MB
  int*   knn    = (int*)(ws + 69632 + 2 * 8388608);       // 1.4 MB
  float* out    = (float*)d_out;

  if (ws_size < (size_t)(69632 + 2 * 8388608 + 16384 * KK * 4)) return;

  k_prep<<<dim3(128), dim3(256), 0, stream>>>(Wf, gf, bf_, mf, vf, Wg, gg, bg, mg, vg,
                                              Wt, beta_f, Wgu, Wgv, beta_g);
  k_geo<<<dim3(4096), dim3(256), 0, stream>>>(xyz, Wgu, Wgv, beta_g, ucat, vcat);
  k_feat<<<dim3(256), dim3(256), 0, stream>>>(f, (const u32*)Wt, beta_f, ucat, vcat);
  k_knn<<<dim3(2048), dim3(256), 0, stream>>>(xyz, knn);
  k_gather<<<dim3(256), dim3(256), 0, stream>>>(ucat, vcat, knn, out);
}

// Round 3
// 293.859 us; speedup vs baseline: 1.1621x; 1.1621x over previous
//
#include <hip/hip_runtime.h>

typedef unsigned int u32;
typedef unsigned long long u64;
typedef unsigned short u16;
typedef float v2f __attribute__((ext_vector_type(2)));

#define DEV __device__ __forceinline__

// ---------- helpers ----------
DEV u16 f2bf(float x) {                      // fp32 -> bf16 RNE
  u32 u = __float_as_uint(x);
  u32 r = u + 0x7fffu + ((u >> 16) & 1u);
  return (u16)(r >> 16);
}
DEV float bflo(u32 d) { return __uint_as_float(d << 16); }
DEV float bfhi(u32 d) { return __uint_as_float(d & 0xffff0000u); }
DEV u64 sortable64(double f) {               // monotonic f64 -> u64
  long long b = __double_as_longlong(f);
  return (u64)b ^ (u64)((b >> 63) | (long long)0x8000000000000000ll);
}
// fp64 exact-selection distance (float products are exact in f64)
DEV double ddist(double qx, double qy, double qz, double qd2,
                 float mxf, float myf, float mzf) {
  double cx = (double)mxf, cy = (double)myf, cz = (double)mzf;
  double cd2 = cx * cx + cy * cy + cz * cz;
  double dot = cx * qx + cy * qy + cz * qz;
  return (qd2 + cd2) - 2.0 * dot;
}
DEV float fmin3f(float a, float b, float c) {   // hope: v_min3_f32
  return __builtin_fminf(__builtin_fminf(a, b), c);
}
DEV v2f vfma2(v2f a, v2f b, v2f c) { return __builtin_elementwise_fma(a, b, c); }

#define NB 2
#define NN 8192
#define NC 128
#define KK 21
// screening metric: st = cd2 - 2*dot (qd2 dropped — per-query constant shift).
// fp32 error vs fp64 <= ~2e-4 on these operand scales; MARGIN covers it so the
// fp64 top-21 set provably survives fp32 screening.
#define MARGIN 1e-3f

// ---------- K0: fold BN into weights ----------
__global__ __launch_bounds__(256) void k_prep(
    const float* __restrict__ Wf, const float* __restrict__ gf, const float* __restrict__ bf_,
    const float* __restrict__ mf, const float* __restrict__ vf,
    const float* __restrict__ Wg, const float* __restrict__ gg, const float* __restrict__ bg,
    const float* __restrict__ mg, const float* __restrict__ vg,
    u16* __restrict__ Wt, float* __restrict__ beta_f,
    float* __restrict__ Wgu, float* __restrict__ Wgv, float* __restrict__ beta_g) {
  int g = blockIdx.x * 256 + threadIdx.x;     // 0..32767
  int c = g >> 8, o = g & 255;
  float val;
  if (o < 128) {
    float inv = gf[o] / sqrtf(vf[o] + 1e-5f);
    val = inv * (Wf[o * 256 + c] - Wf[o * 256 + c + 128]);
  } else {
    int o2 = o - 128;
    float inv = gf[o2] / sqrtf(vf[o2] + 1e-5f);
    val = inv * Wf[o2 * 256 + c + 128];
  }
  Wt[c * 256 + o] = f2bf(val);
  if (g < 128) {
    float inv = gf[g] / sqrtf(vf[g] + 1e-5f);
    beta_f[g] = bf_[g] - mf[g] * inv;
  } else if (g < 256) {
    int oo = g - 128;
    float invg = gg[oo] / sqrtf(vg[oo] + 1e-5f);
#pragma unroll
    for (int d = 0; d < 3; ++d) {
      Wgu[oo * 3 + d] = invg * (Wg[oo * 6 + d] - Wg[oo * 6 + 3 + d]);
      Wgv[oo * 3 + d] = invg * Wg[oo * 6 + 3 + d];
    }
    beta_g[oo] = bg[oo] - mg[oo] * invg;
  }
}

// ---------- K1geo ----------
__global__ __launch_bounds__(256) void k_geo(
    const float* __restrict__ xyz, const float* __restrict__ Wgu, const float* __restrict__ Wgv,
    const float* __restrict__ beta_g, u32* __restrict__ ucat, u32* __restrict__ vcat) {
  int g = blockIdx.x * 256 + threadIdx.x;     // < 16384*64
  int p = g >> 6, oc = g & 63;
  const float* xp = xyz + p * 3;
  float X = xp[0], Y = xp[1], Z = xp[2];
  u32 du = 0, dv = 0;
#pragma unroll
  for (int h = 0; h < 2; ++h) {
    int o = oc * 2 + h;
    float ug = X * Wgu[o * 3] + Y * Wgu[o * 3 + 1] + Z * Wgu[o * 3 + 2] + beta_g[o];
    float vv = X * Wgv[o * 3] + Y * Wgv[o * 3 + 1] + Z * Wgv[o * 3 + 2];
    du |= (u32)f2bf(ug) << (16 * h);
    dv |= (u32)f2bf(vv) << (16 * h);
  }
  ucat[p * 128 + oc] = du;
  vcat[p * 128 + oc] = dv;
}

// ---------- K1f: feat branch GEMM ----------
__global__ __launch_bounds__(256) void k_feat(
    const float* __restrict__ f, const u32* __restrict__ Wt32, const float* __restrict__ beta_f,
    u32* __restrict__ ucat, u32* __restrict__ vcat) {
  __shared__ u32 sW[128 * 128];
  __shared__ float sF[128][68];

  const int t = threadIdx.x;
  const int b = blockIdx.x >> 7;
  const int n0 = (blockIdx.x & 127) << 6;
  const int boff = b * (NC * NN);

#pragma unroll
  for (int k = 0; k < 64; ++k) sW[t + (k << 8)] = Wt32[t + (k << 8)];
#pragma unroll
  for (int k = 0; k < 32; ++k) {
    int i = t + (k << 8);
    int c = i >> 6, col = i & 63;
    sF[c][col] = f[boff + c * NN + n0 + col];
  }
  __syncthreads();

  const int w = t >> 6, lane = t & 63;
  const int og = lane >> 3, pg = lane & 7;
  const int o0 = w * 64 + og * 8;
  const int p0 = pg * 8;

  float acc[8][8];
#pragma unroll
  for (int a = 0; a < 8; ++a)
#pragma unroll
    for (int p = 0; p < 8; ++p) acc[a][p] = 0.0f;

  for (int c = 0; c < 128; ++c) {
    float4 fa = *(const float4*)&sF[c][p0];
    float4 fb = *(const float4*)&sF[c][p0 + 4];
    uint4 wr = *(const uint4*)&sW[c * 128 + (o0 >> 1)];
    float wv[8] = {bflo(wr.x), bfhi(wr.x), bflo(wr.y), bfhi(wr.y),
                   bflo(wr.z), bfhi(wr.z), bflo(wr.w), bfhi(wr.w)};
    float fv[8] = {fa.x, fa.y, fa.z, fa.w, fb.x, fb.y, fb.z, fb.w};
#pragma unroll
    for (int a = 0; a < 8; ++a)
#pragma unroll
      for (int p = 0; p < 8; ++p) acc[a][p] = __builtin_fmaf(wv[a], fv[p], acc[a][p]);
  }

  const int ochan = o0 & 127;
  const bool is_u = (o0 < 128);
  float bet[8];
#pragma unroll
  for (int a = 0; a < 8; ++a) bet[a] = is_u ? beta_f[ochan + a] : 0.0f;
  u32* dstbase = is_u ? ucat : vcat;
#pragma unroll
  for (int p = 0; p < 8; ++p) {
    int pt = (b << 13) + n0 + p0 + p;
    u32 d0 = (u32)f2bf(acc[0][p] + bet[0]) | ((u32)f2bf(acc[1][p] + bet[1]) << 16);
    u32 d1 = (u32)f2bf(acc[2][p] + bet[2]) | ((u32)f2bf(acc[3][p] + bet[3]) << 16);
    u32 d2 = (u32)f2bf(acc[4][p] + bet[4]) | ((u32)f2bf(acc[5][p] + bet[5]) << 16);
    u32 d3 = (u32)f2bf(acc[6][p] + bet[6]) | ((u32)f2bf(acc[7][p] + bet[7]) << 16);
    *(uint4*)&dstbase[pt * 128 + 64 + (ochan >> 1)] = make_uint4(d0, d1, d2, d3);
  }
}

// ---------- K2: exact KNN (k=21) ----------
// Structure from r2 (2048 blocks, 8 q/block, wave = all 8 q x quarter cands):
// occupancy rose 36->73% as predicted, but __launch_bounds__(256,8) capped
// VGPRs at 64 and the allocator collapsed to 32 + scratch spill (FETCH 437MB).
// Fix: (256,6) -> 85-VGPR budget, comfortably above the ~60 live regs, no
// spill; LDS 18.9KB allows 8 blocks/CU if regs land <=64. Code otherwise
// byte-identical to r2 for clean attribution.
__global__ __launch_bounds__(256, 6) void k_knn(const float* __restrict__ xyz,
                                                int* __restrict__ knn) {
  __shared__ float sx[1024], sy[1024], sz[1024], sd[1024];   // 16 KB SoA tile
  __shared__ u16 ssurv[8][128];                              // 2 KB
  __shared__ u32 scnt[8];
  __shared__ float sthr[4][8];

  const int t = threadIdx.x;
  const int blk = blockIdx.x;                 // 0..2047
  const int b = blk >> 10;                    // 1024 blocks per batch
  const int n0 = (blk & 1023) << 3;           // 8 queries per block
  const float* X = xyz + b * (NN * 3);

  if (t < 8) scnt[t] = 0u;

  const int w = t >> 6, lane = t & 63;
  const int ci = (w << 8) + (lane << 2);      // this lane's 4 candidates in tile

  float mx[8], my[8], mz[8], mn[8];
#pragma unroll
  for (int i = 0; i < 8; ++i) {
    int q = n0 + i;
    mx[i] = -2.0f * X[q * 3];
    my[i] = -2.0f * X[q * 3 + 1];
    mz[i] = -2.0f * X[q * 3 + 2];
    mn[i] = __builtin_inff();
  }

  // ---- pass A: per-lane running min of st = cd2 - 2*dot (this wave's quarter) ----
  for (int ct = 0; ct < 8; ++ct) {
    __syncthreads();                          // guard tile buffer reuse
    {
      const float* src = X + ct * 3072 + t * 12;
      float4 q0 = *(const float4*)(src);      // x0 y0 z0 x1
      float4 q1 = *(const float4*)(src + 4);  // y1 z1 x2 y2
      float4 q2 = *(const float4*)(src + 8);  // z2 x3 y3 z3
      int c0 = t << 2;
      *(float4*)&sx[c0] = make_float4(q0.x, q0.w, q1.z, q2.y);
      *(float4*)&sy[c0] = make_float4(q0.y, q1.x, q1.w, q2.z);
      *(float4*)&sz[c0] = make_float4(q0.z, q1.y, q2.x, q2.w);
      v2f x01 = {q0.x, q0.w}, x23 = {q1.z, q2.y};
      v2f y01 = {q0.y, q1.x}, y23 = {q1.w, q2.z};
      v2f z01 = {q0.z, q1.y}, z23 = {q2.x, q2.w};
      v2f w01 = vfma2(x01, x01, vfma2(y01, y01, z01 * z01));
      v2f w23 = vfma2(x23, x23, vfma2(y23, y23, z23 * z23));
      *(float4*)&sd[c0] = make_float4(w01.x, w01.y, w23.x, w23.y);
    }
    __syncthreads();
    float4 X4 = *(const float4*)&sx[ci];
    float4 Y4 = *(const float4*)&sy[ci];
    float4 Z4 = *(const float4*)&sz[ci];
    float4 D4 = *(const float4*)&sd[ci];
    v2f x01 = {X4.x, X4.y}, x23 = {X4.z, X4.w};
    v2f y01 = {Y4.x, Y4.y}, y23 = {Y4.z, Y4.w};
    v2f z01 = {Z4.x, Z4.y}, z23 = {Z4.z, Z4.w};
    v2f w01 = {D4.x, D4.y}, w23 = {D4.z, D4.w};
#pragma unroll
    for (int i = 0; i < 8; ++i) {
      v2f mxv = {mx[i], mx[i]}, myv = {my[i], my[i]}, mzv = {mz[i], mz[i]};
      v2f s01 = vfma2(x01, mxv, vfma2(y01, myv, vfma2(z01, mzv, w01)));
      v2f s23 = vfma2(x23, mxv, vfma2(y23, myv, vfma2(z23, mzv, w23)));
      mn[i] = fmin3f(mn[i], s01.x, s01.y);
      mn[i] = fmin3f(mn[i], s23.x, s23.y);
    }
  }

  // ---- threshold: 21st smallest of 64 disjoint-subset lane minima per quarter,
  //      then min across the four quarters ----
#pragma unroll 1
  for (int i = 0; i < 8; ++i) {
    float v = mn[i];
#pragma unroll
    for (int k = 2; k <= 64; k <<= 1) {
#pragma unroll
      for (int j = k >> 1; j > 0; j >>= 1) {
        float p = __shfl_xor(v, j);
        bool takeMin = (((lane & k) == 0) == ((lane & j) == 0));
        v = takeMin ? fminf(v, p) : fmaxf(v, p);
      }
    }
    float tw = __shfl(v, 20);
    if (lane == 0) sthr[w][i] = tw;
  }
  __syncthreads();
  float thr[8];
#pragma unroll
  for (int i = 0; i < 8; ++i)
    thr[i] = fminf(fminf(sthr[0][i], sthr[1][i]),
                   fminf(sthr[2][i], sthr[3][i])) + MARGIN;

  // ---- pass B: compact survivors (identical staged values as pass A) ----
  for (int ct = 0; ct < 8; ++ct) {
    __syncthreads();
    {
      const float* src = X + ct * 3072 + t * 12;
      float4 q0 = *(const float4*)(src);
      float4 q1 = *(const float4*)(src + 4);
      float4 q2 = *(const float4*)(src + 8);
      int c0 = t << 2;
      *(float4*)&sx[c0] = make_float4(q0.x, q0.w, q1.z, q2.y);
      *(float4*)&sy[c0] = make_float4(q0.y, q1.x, q1.w, q2.z);
      *(float4*)&sz[c0] = make_float4(q0.z, q1.y, q2.x, q2.w);
      v2f x01 = {q0.x, q0.w}, x23 = {q1.z, q2.y};
      v2f y01 = {q0.y, q1.x}, y23 = {q1.w, q2.z};
      v2f z01 = {q0.z, q1.y}, z23 = {q2.x, q2.w};
      v2f w01 = vfma2(x01, x01, vfma2(y01, y01, z01 * z01));
      v2f w23 = vfma2(x23, x23, vfma2(y23, y23, z23 * z23));
      *(float4*)&sd[c0] = make_float4(w01.x, w01.y, w23.x, w23.y);
    }
    __syncthreads();
    float4 X4 = *(const float4*)&sx[ci];
    float4 Y4 = *(const float4*)&sy[ci];
    float4 Z4 = *(const float4*)&sz[ci];
    float4 D4 = *(const float4*)&sd[ci];
    v2f x01 = {X4.x, X4.y}, x23 = {X4.z, X4.w};
    v2f y01 = {Y4.x, Y4.y}, y23 = {Y4.z, Y4.w};
    v2f z01 = {Z4.x, Z4.y}, z23 = {Z4.z, Z4.w};
    v2f w01 = {D4.x, D4.y}, w23 = {D4.z, D4.w};
    const int mbase = ct * 1024 + ci;
#pragma unroll
    for (int i = 0; i < 8; ++i) {
      v2f mxv = {mx[i], mx[i]}, myv = {my[i], my[i]}, mzv = {mz[i], mz[i]};
      v2f s01 = vfma2(x01, mxv, vfma2(y01, myv, vfma2(z01, mzv, w01)));
      v2f s23 = vfma2(x23, mxv, vfma2(y23, myv, vfma2(z23, mzv, w23)));
      float worst = fminf(fmin3f(s01.x, s01.y, s23.x), s23.y);
      if (worst <= thr[i]) {                  // rare-taken: one branch per (q,4c)
        if (s01.x <= thr[i]) {
          u32 slot = atomicAdd(&scnt[i], 1u);
          if (slot < 128u) ssurv[i][slot] = (u16)(mbase + 0);
        }
        if (s01.y <= thr[i]) {
          u32 slot = atomicAdd(&scnt[i], 1u);
          if (slot < 128u) ssurv[i][slot] = (u16)(mbase + 1);
        }
        if (s23.x <= thr[i]) {
          u32 slot = atomicAdd(&scnt[i], 1u);
          if (slot < 128u) ssurv[i][slot] = (u16)(mbase + 2);
        }
        if (s23.y <= thr[i]) {
          u32 slot = atomicAdd(&scnt[i], 1u);
          if (slot < 128u) ssurv[i][slot] = (u16)(mbase + 3);
        }
      }
    }
  }
  __syncthreads();

  // ---- selection: exact top-21 by fp64 (dist, idx); 2 queries per wave ----
#pragma unroll 1
  for (int i = 0; i < 2; ++i) {
    const int qq = (w << 1) + i;
    const int q = n0 + qq;
    double Qx = (double)X[q * 3], Qy = (double)X[q * 3 + 1], Qz = (double)X[q * 3 + 2];
    double Qd2 = Qx * Qx + Qy * Qy + Qz * Qz;
    u32 cnt = scnt[qq];
    if (cnt > 128u) cnt = 128u;
    int* outp = knn + ((b << 13) + q) * KK;

    bool v0 = ((u32)lane < cnt);
    u32 m0 = v0 ? (u32)ssurv[qq][lane] : 0u;
    double s0 = ddist(Qx, Qy, Qz, Qd2, X[m0 * 3], X[m0 * 3 + 1], X[m0 * 3 + 2]);
    // key: fp64-sortable, low 13 bits replaced by idx (lowest-index tie-break)
    u64 k0 = v0 ? ((sortable64(s0) & 0xFFFFFFFFFFFFE000ull) | (u64)m0) : ~0ull;

    if (cnt <= 64u) {
      u64 v = k0;
#pragma unroll
      for (int k = 2; k <= 64; k <<= 1) {
#pragma unroll
        for (int j = k >> 1; j > 0; j >>= 1) {
          u64 p = __shfl_xor(v, j);
          bool takeMin = (((lane & k) == 0) == ((lane & j) == 0));
          bool pl = p < v;
          u64 mnv = pl ? p : v;
          u64 mxv = pl ? v : p;
          v = takeMin ? mnv : mxv;
        }
      }
      if (lane < KK) outp[lane] = (int)(v & 8191ull);
    } else {
      bool v1 = ((u32)(lane + 64) < cnt);
      u32 m1 = v1 ? (u32)ssurv[qq][lane + 64] : 0u;
      double s1 = ddist(Qx, Qy, Qz, Qd2, X[m1 * 3], X[m1 * 3 + 1], X[m1 * 3 + 2]);
      u64 k1 = v1 ? ((sortable64(s1) & 0xFFFFFFFFFFFFE000ull) | (u64)m1) : ~0ull;
      u32 selm = 0;
      for (int r = 0; r < KK; ++r) {
        u64 mk = (k0 < k1) ? k0 : k1;
#pragma unroll
        for (int j = 32; j > 0; j >>= 1) {
          u64 p = __shfl_xor(mk, j);
          if (p < mk) mk = p;
        }
        if (k0 == mk) k0 = ~0ull;
        else if (k1 == mk) k1 = ~0ull;
        if (lane == r) selm = (u32)(mk & 8191ull);
      }
      if (lane < KK) outp[lane] = (int)selm;
    }
  }
}

// ---------- K3: gather + max + relu + transpose-write ----------
__global__ __launch_bounds__(256) void k_gather(
    const u32* __restrict__ ucat, const u32* __restrict__ vcat,
    const int* __restrict__ knn, float* __restrict__ out) {
  __shared__ float tr[64 * 258];

  const int t = threadIdx.x;
  const int b = blockIdx.x >> 7;
  const int n0 = (blockIdx.x & 127) << 6;
  const int w = t >> 6, lane = t & 63;
  const int which = w >> 1;
  const int lo = ((w & 1) << 6) | lane;

  for (int step = 0; step < 32; ++step) {
    int qq = step * 2 + which;
    int q = n0 + qq;
    const int* ip = knn + ((b << 13) + q) * KK;
    float a0 = -__builtin_inff(), a1 = -__builtin_inff();
#pragma unroll
    for (int k = 0; k < KK; ++k) {
      int p = ip[k];
      u32 d = vcat[(((b << 13) + p) << 7) + lo];
      a0 = fmaxf(a0, bflo(d));
      a1 = fmaxf(a1, bfhi(d));
    }
    u32 u = ucat[(((b << 13) + q) << 7) + lo];
    float r0 = fmaxf(bflo(u) + a0, 0.0f);
    float r1 = fmaxf(bfhi(u) + a1, 0.0f);
    *(float2*)&tr[qq * 258 + 2 * lo] = make_float2(r0, r1);
  }
  __syncthreads();

  float* ob = out + b * (256 * NN);
  for (int i = 0; i < 64; ++i) {
    int o = (w << 6) + i;
    ob[o * NN + n0 + lane] = tr[lane * 258 + o];
  }
}

// ---------- launch ----------
extern "C" void kernel_launch(void* const* d_in, const int* in_sizes, int n_in,
                              void* d_out, int out_size, void* d_ws, size_t ws_size,
                              hipStream_t stream) {
  const float* xyz = (const float*)d_in[0];
  const float* f   = (const float*)d_in[1];
  const float* Wg  = (const float*)d_in[2];
  const float* gg  = (const float*)d_in[3];
  const float* bg  = (const float*)d_in[4];
  const float* mg  = (const float*)d_in[5];
  const float* vg  = (const float*)d_in[6];
  const float* Wf  = (const float*)d_in[7];
  const float* gf  = (const float*)d_in[8];
  const float* bf_ = (const float*)d_in[9];
  const float* mf  = (const float*)d_in[10];
  const float* vf  = (const float*)d_in[11];

  char* ws = (char*)d_ws;
  u16*   Wt     = (u16*)ws;                               // 65536 B
  float* beta_f = (float*)(ws + 65536);
  float* Wgu    = (float*)(ws + 66048);
  float* Wgv    = (float*)(ws + 67584);
  float* beta_g = (float*)(ws + 69120);
  u32*   ucat   = (u32*)(ws + 69632);                     // 8 MB
  u32*   vcat   = (u32*)(ws + 69632 + 8388608);           // 8 MB
  int*   knn    = (int*)(ws + 69632 + 2 * 8388608);       // 1.4 MB
  float* out    = (float*)d_out;

  if (ws_size < (size_t)(69632 + 2 * 8388608 + 16384 * KK * 4)) return;

  k_prep<<<dim3(128), dim3(256), 0, stream>>>(Wf, gf, bf_, mf, vf, Wg, gg, bg, mg, vg,
                                              Wt, beta_f, Wgu, Wgv, beta_g);
  k_geo<<<dim3(4096), dim3(256), 0, stream>>>(xyz, Wgu, Wgv, beta_g, ucat, vcat);
  k_feat<<<dim3(256), dim3(256), 0, stream>>>(f, (const u32*)Wt, beta_f, ucat, vcat);
  k_knn<<<dim3(2048), dim3(256), 0, stream>>>(xyz, knn);
  k_gather<<<dim3(256), dim3(256), 0, stream>>>(ucat, vcat, knn, out);
}

// Round 4
// 271.845 us; speedup vs baseline: 1.2563x; 1.0810x over previous
//
#include <hip/hip_runtime.h>

typedef unsigned int u32;
typedef unsigned long long u64;
typedef unsigned short u16;
typedef float v2f __attribute__((ext_vector_type(2)));

#define DEV __device__ __forceinline__

// ---------- helpers ----------
DEV u16 f2bf(float x) {                      // fp32 -> bf16 RNE
  u32 u = __float_as_uint(x);
  u32 r = u + 0x7fffu + ((u >> 16) & 1u);
  return (u16)(r >> 16);
}
DEV float bflo(u32 d) { return __uint_as_float(d << 16); }
DEV float bfhi(u32 d) { return __uint_as_float(d & 0xffff0000u); }
DEV u64 sortable64(double f) {               // monotonic f64 -> u64
  long long b = __double_as_longlong(f);
  return (u64)b ^ (u64)((b >> 63) | (long long)0x8000000000000000ll);
}
// fp64 exact-selection distance (float products are exact in f64)
DEV double ddist(double qx, double qy, double qz, double qd2,
                 float mxf, float myf, float mzf) {
  double cx = (double)mxf, cy = (double)myf, cz = (double)mzf;
  double cd2 = cx * cx + cy * cy + cz * cz;
  double dot = cx * qx + cy * qy + cz * qz;
  return (qd2 + cd2) - 2.0 * dot;
}
DEV float fmin3f(float a, float b, float c) {   // hope: v_min3_f32
  return __builtin_fminf(__builtin_fminf(a, b), c);
}
DEV v2f vfma2(v2f a, v2f b, v2f c) { return __builtin_elementwise_fma(a, b, c); }

#define NB 2
#define NN 8192
#define NC 128
#define KK 21
// screening metric: st = cd2 - 2*dot (qd2 dropped — per-query constant shift).
// fp32 error vs fp64 <= ~2e-4 on these operand scales; MARGIN covers it so the
// fp64 top-21 set provably survives fp32 screening.
#define MARGIN 1e-3f

// ---------- K0: fold BN into weights ----------
__global__ __launch_bounds__(256) void k_prep(
    const float* __restrict__ Wf, const float* __restrict__ gf, const float* __restrict__ bf_,
    const float* __restrict__ mf, const float* __restrict__ vf,
    const float* __restrict__ Wg, const float* __restrict__ gg, const float* __restrict__ bg,
    const float* __restrict__ mg, const float* __restrict__ vg,
    u16* __restrict__ Wt, float* __restrict__ beta_f,
    float* __restrict__ Wgu, float* __restrict__ Wgv, float* __restrict__ beta_g) {
  int g = blockIdx.x * 256 + threadIdx.x;     // 0..32767
  int c = g >> 8, o = g & 255;
  float val;
  if (o < 128) {
    float inv = gf[o] / sqrtf(vf[o] + 1e-5f);
    val = inv * (Wf[o * 256 + c] - Wf[o * 256 + c + 128]);
  } else {
    int o2 = o - 128;
    float inv = gf[o2] / sqrtf(vf[o2] + 1e-5f);
    val = inv * Wf[o2 * 256 + c + 128];
  }
  Wt[c * 256 + o] = f2bf(val);
  if (g < 128) {
    float inv = gf[g] / sqrtf(vf[g] + 1e-5f);
    beta_f[g] = bf_[g] - mf[g] * inv;
  } else if (g < 256) {
    int oo = g - 128;
    float invg = gg[oo] / sqrtf(vg[oo] + 1e-5f);
#pragma unroll
    for (int d = 0; d < 3; ++d) {
      Wgu[oo * 3 + d] = invg * (Wg[oo * 6 + d] - Wg[oo * 6 + 3 + d]);
      Wgv[oo * 3 + d] = invg * Wg[oo * 6 + 3 + d];
    }
    beta_g[oo] = bg[oo] - mg[oo] * invg;
  }
}

// ---------- K1geo ----------
__global__ __launch_bounds__(256) void k_geo(
    const float* __restrict__ xyz, const float* __restrict__ Wgu, const float* __restrict__ Wgv,
    const float* __restrict__ beta_g, u32* __restrict__ ucat, u32* __restrict__ vcat) {
  int g = blockIdx.x * 256 + threadIdx.x;     // < 16384*64
  int p = g >> 6, oc = g & 63;
  const float* xp = xyz + p * 3;
  float X = xp[0], Y = xp[1], Z = xp[2];
  u32 du = 0, dv = 0;
#pragma unroll
  for (int h = 0; h < 2; ++h) {
    int o = oc * 2 + h;
    float ug = X * Wgu[o * 3] + Y * Wgu[o * 3 + 1] + Z * Wgu[o * 3 + 2] + beta_g[o];
    float vv = X * Wgv[o * 3] + Y * Wgv[o * 3 + 1] + Z * Wgv[o * 3 + 2];
    du |= (u32)f2bf(ug) << (16 * h);
    dv |= (u32)f2bf(vv) << (16 * h);
  }
  ucat[p * 128 + oc] = du;
  vcat[p * 128 + oc] = dv;
}

// ---------- K1f: feat branch GEMM ----------
__global__ __launch_bounds__(256) void k_feat(
    const float* __restrict__ f, const u32* __restrict__ Wt32, const float* __restrict__ beta_f,
    u32* __restrict__ ucat, u32* __restrict__ vcat) {
  __shared__ u32 sW[128 * 128];
  __shared__ float sF[128][68];

  const int t = threadIdx.x;
  const int b = blockIdx.x >> 7;
  const int n0 = (blockIdx.x & 127) << 6;
  const int boff = b * (NC * NN);

#pragma unroll
  for (int k = 0; k < 64; ++k) sW[t + (k << 8)] = Wt32[t + (k << 8)];
#pragma unroll
  for (int k = 0; k < 32; ++k) {
    int i = t + (k << 8);
    int c = i >> 6, col = i & 63;
    sF[c][col] = f[boff + c * NN + n0 + col];
  }
  __syncthreads();

  const int w = t >> 6, lane = t & 63;
  const int og = lane >> 3, pg = lane & 7;
  const int o0 = w * 64 + og * 8;
  const int p0 = pg * 8;

  float acc[8][8];
#pragma unroll
  for (int a = 0; a < 8; ++a)
#pragma unroll
    for (int p = 0; p < 8; ++p) acc[a][p] = 0.0f;

  for (int c = 0; c < 128; ++c) {
    float4 fa = *(const float4*)&sF[c][p0];
    float4 fb = *(const float4*)&sF[c][p0 + 4];
    uint4 wr = *(const uint4*)&sW[c * 128 + (o0 >> 1)];
    float wv[8] = {bflo(wr.x), bfhi(wr.x), bflo(wr.y), bfhi(wr.y),
                   bflo(wr.z), bfhi(wr.z), bflo(wr.w), bfhi(wr.w)};
    float fv[8] = {fa.x, fa.y, fa.z, fa.w, fb.x, fb.y, fb.z, fb.w};
#pragma unroll
    for (int a = 0; a < 8; ++a)
#pragma unroll
      for (int p = 0; p < 8; ++p) acc[a][p] = __builtin_fmaf(wv[a], fv[p], acc[a][p]);
  }

  const int ochan = o0 & 127;
  const bool is_u = (o0 < 128);
  float bet[8];
#pragma unroll
  for (int a = 0; a < 8; ++a) bet[a] = is_u ? beta_f[ochan + a] : 0.0f;
  u32* dstbase = is_u ? ucat : vcat;
#pragma unroll
  for (int p = 0; p < 8; ++p) {
    int pt = (b << 13) + n0 + p0 + p;
    u32 d0 = (u32)f2bf(acc[0][p] + bet[0]) | ((u32)f2bf(acc[1][p] + bet[1]) << 16);
    u32 d1 = (u32)f2bf(acc[2][p] + bet[2]) | ((u32)f2bf(acc[3][p] + bet[3]) << 16);
    u32 d2 = (u32)f2bf(acc[4][p] + bet[4]) | ((u32)f2bf(acc[5][p] + bet[5]) << 16);
    u32 d3 = (u32)f2bf(acc[6][p] + bet[6]) | ((u32)f2bf(acc[7][p] + bet[7]) << 16);
    *(uint4*)&dstbase[pt * 128 + 64 + (ochan >> 1)] = make_uint4(d0, d1, d2, d3);
  }
}

// ---------- K2: exact KNN (k=21) ----------
// r2/r3 lesson: hipcc budgets VGPRs as 256/min_waves for the 2nd launch_bounds
// arg (empirical: (256,8)->32 VGPR, (256,6)->40 VGPR, both spilling to
// scratch: 437MB/40MB HBM WRITE). Plain __launch_bounds__(256) compiled this
// register footprint to 52 VGPRs with zero scratch in r0/r1; at <=64 VGPRs the
// HW gives 8 waves/SIMD anyway (512-VGPR/SIMD pool), LDS 18.9KB allows 8
// blocks/CU, grid 2048 = 8 blocks/CU. Code otherwise identical to r2/r3.
__global__ __launch_bounds__(256) void k_knn(const float* __restrict__ xyz,
                                             int* __restrict__ knn) {
  __shared__ float sx[1024], sy[1024], sz[1024], sd[1024];   // 16 KB SoA tile
  __shared__ u16 ssurv[8][128];                              // 2 KB
  __shared__ u32 scnt[8];
  __shared__ float sthr[4][8];

  const int t = threadIdx.x;
  const int blk = blockIdx.x;                 // 0..2047
  const int b = blk >> 10;                    // 1024 blocks per batch
  const int n0 = (blk & 1023) << 3;           // 8 queries per block
  const float* X = xyz + b * (NN * 3);

  if (t < 8) scnt[t] = 0u;

  const int w = t >> 6, lane = t & 63;
  const int ci = (w << 8) + (lane << 2);      // this lane's 4 candidates in tile

  float mx[8], my[8], mz[8], mn[8];
#pragma unroll
  for (int i = 0; i < 8; ++i) {
    int q = n0 + i;
    mx[i] = -2.0f * X[q * 3];
    my[i] = -2.0f * X[q * 3 + 1];
    mz[i] = -2.0f * X[q * 3 + 2];
    mn[i] = __builtin_inff();
  }

  // ---- pass A: per-lane running min of st = cd2 - 2*dot (this wave's quarter) ----
  for (int ct = 0; ct < 8; ++ct) {
    __syncthreads();                          // guard tile buffer reuse
    {
      const float* src = X + ct * 3072 + t * 12;
      float4 q0 = *(const float4*)(src);      // x0 y0 z0 x1
      float4 q1 = *(const float4*)(src + 4);  // y1 z1 x2 y2
      float4 q2 = *(const float4*)(src + 8);  // z2 x3 y3 z3
      int c0 = t << 2;
      *(float4*)&sx[c0] = make_float4(q0.x, q0.w, q1.z, q2.y);
      *(float4*)&sy[c0] = make_float4(q0.y, q1.x, q1.w, q2.z);
      *(float4*)&sz[c0] = make_float4(q0.z, q1.y, q2.x, q2.w);
      v2f x01 = {q0.x, q0.w}, x23 = {q1.z, q2.y};
      v2f y01 = {q0.y, q1.x}, y23 = {q1.w, q2.z};
      v2f z01 = {q0.z, q1.y}, z23 = {q2.x, q2.w};
      v2f w01 = vfma2(x01, x01, vfma2(y01, y01, z01 * z01));
      v2f w23 = vfma2(x23, x23, vfma2(y23, y23, z23 * z23));
      *(float4*)&sd[c0] = make_float4(w01.x, w01.y, w23.x, w23.y);
    }
    __syncthreads();
    float4 X4 = *(const float4*)&sx[ci];
    float4 Y4 = *(const float4*)&sy[ci];
    float4 Z4 = *(const float4*)&sz[ci];
    float4 D4 = *(const float4*)&sd[ci];
    v2f x01 = {X4.x, X4.y}, x23 = {X4.z, X4.w};
    v2f y01 = {Y4.x, Y4.y}, y23 = {Y4.z, Y4.w};
    v2f z01 = {Z4.x, Z4.y}, z23 = {Z4.z, Z4.w};
    v2f w01 = {D4.x, D4.y}, w23 = {D4.z, D4.w};
#pragma unroll
    for (int i = 0; i < 8; ++i) {
      v2f mxv = {mx[i], mx[i]}, myv = {my[i], my[i]}, mzv = {mz[i], mz[i]};
      v2f s01 = vfma2(x01, mxv, vfma2(y01, myv, vfma2(z01, mzv, w01)));
      v2f s23 = vfma2(x23, mxv, vfma2(y23, myv, vfma2(z23, mzv, w23)));
      mn[i] = fmin3f(mn[i], s01.x, s01.y);
      mn[i] = fmin3f(mn[i], s23.x, s23.y);
    }
  }

  // ---- threshold: 21st smallest of 64 disjoint-subset lane minima per quarter,
  //      then min across the four quarters ----
#pragma unroll 1
  for (int i = 0; i < 8; ++i) {
    float v = mn[i];
#pragma unroll
    for (int k = 2; k <= 64; k <<= 1) {
#pragma unroll
      for (int j = k >> 1; j > 0; j >>= 1) {
        float p = __shfl_xor(v, j);
        bool takeMin = (((lane & k) == 0) == ((lane & j) == 0));
        v = takeMin ? fminf(v, p) : fmaxf(v, p);
      }
    }
    float tw = __shfl(v, 20);
    if (lane == 0) sthr[w][i] = tw;
  }
  __syncthreads();
  float thr[8];
#pragma unroll
  for (int i = 0; i < 8; ++i)
    thr[i] = fminf(fminf(sthr[0][i], sthr[1][i]),
                   fminf(sthr[2][i], sthr[3][i])) + MARGIN;

  // ---- pass B: compact survivors (identical staged values as pass A) ----
  for (int ct = 0; ct < 8; ++ct) {
    __syncthreads();
    {
      const float* src = X + ct * 3072 + t * 12;
      float4 q0 = *(const float4*)(src);
      float4 q1 = *(const float4*)(src + 4);
      float4 q2 = *(const float4*)(src + 8);
      int c0 = t << 2;
      *(float4*)&sx[c0] = make_float4(q0.x, q0.w, q1.z, q2.y);
      *(float4*)&sy[c0] = make_float4(q0.y, q1.x, q1.w, q2.z);
      *(float4*)&sz[c0] = make_float4(q0.z, q1.y, q2.x, q2.w);
      v2f x01 = {q0.x, q0.w}, x23 = {q1.z, q2.y};
      v2f y01 = {q0.y, q1.x}, y23 = {q1.w, q2.z};
      v2f z01 = {q0.z, q1.y}, z23 = {q2.x, q2.w};
      v2f w01 = vfma2(x01, x01, vfma2(y01, y01, z01 * z01));
      v2f w23 = vfma2(x23, x23, vfma2(y23, y23, z23 * z23));
      *(float4*)&sd[c0] = make_float4(w01.x, w01.y, w23.x, w23.y);
    }
    __syncthreads();
    float4 X4 = *(const float4*)&sx[ci];
    float4 Y4 = *(const float4*)&sy[ci];
    float4 Z4 = *(const float4*)&sz[ci];
    float4 D4 = *(const float4*)&sd[ci];
    v2f x01 = {X4.x, X4.y}, x23 = {X4.z, X4.w};
    v2f y01 = {Y4.x, Y4.y}, y23 = {Y4.z, Y4.w};
    v2f z01 = {Z4.x, Z4.y}, z23 = {Z4.z, Z4.w};
    v2f w01 = {D4.x, D4.y}, w23 = {D4.z, D4.w};
    const int mbase = ct * 1024 + ci;
#pragma unroll
    for (int i = 0; i < 8; ++i) {
      v2f mxv = {mx[i], mx[i]}, myv = {my[i], my[i]}, mzv = {mz[i], mz[i]};
      v2f s01 = vfma2(x01, mxv, vfma2(y01, myv, vfma2(z01, mzv, w01)));
      v2f s23 = vfma2(x23, mxv, vfma2(y23, myv, vfma2(z23, mzv, w23)));
      float worst = fminf(fmin3f(s01.x, s01.y, s23.x), s23.y);
      if (worst <= thr[i]) {                  // rare-taken: one branch per (q,4c)
        if (s01.x <= thr[i]) {
          u32 slot = atomicAdd(&scnt[i], 1u);
          if (slot < 128u) ssurv[i][slot] = (u16)(mbase + 0);
        }
        if (s01.y <= thr[i]) {
          u32 slot = atomicAdd(&scnt[i], 1u);
          if (slot < 128u) ssurv[i][slot] = (u16)(mbase + 1);
        }
        if (s23.x <= thr[i]) {
          u32 slot = atomicAdd(&scnt[i], 1u);
          if (slot < 128u) ssurv[i][slot] = (u16)(mbase + 2);
        }
        if (s23.y <= thr[i]) {
          u32 slot = atomicAdd(&scnt[i], 1u);
          if (slot < 128u) ssurv[i][slot] = (u16)(mbase + 3);
        }
      }
    }
  }
  __syncthreads();

  // ---- selection: exact top-21 by fp64 (dist, idx); 2 queries per wave ----
#pragma unroll 1
  for (int i = 0; i < 2; ++i) {
    const int qq = (w << 1) + i;
    const int q = n0 + qq;
    double Qx = (double)X[q * 3], Qy = (double)X[q * 3 + 1], Qz = (double)X[q * 3 + 2];
    double Qd2 = Qx * Qx + Qy * Qy + Qz * Qz;
    u32 cnt = scnt[qq];
    if (cnt > 128u) cnt = 128u;
    int* outp = knn + ((b << 13) + q) * KK;

    bool v0 = ((u32)lane < cnt);
    u32 m0 = v0 ? (u32)ssurv[qq][lane] : 0u;
    double s0 = ddist(Qx, Qy, Qz, Qd2, X[m0 * 3], X[m0 * 3 + 1], X[m0 * 3 + 2]);
    // key: fp64-sortable, low 13 bits replaced by idx (lowest-index tie-break)
    u64 k0 = v0 ? ((sortable64(s0) & 0xFFFFFFFFFFFFE000ull) | (u64)m0) : ~0ull;

    if (cnt <= 64u) {
      u64 v = k0;
#pragma unroll
      for (int k = 2; k <= 64; k <<= 1) {
#pragma unroll
        for (int j = k >> 1; j > 0; j >>= 1) {
          u64 p = __shfl_xor(v, j);
          bool takeMin = (((lane & k) == 0) == ((lane & j) == 0));
          bool pl = p < v;
          u64 mnv = pl ? p : v;
          u64 mxv = pl ? v : p;
          v = takeMin ? mnv : mxv;
        }
      }
      if (lane < KK) outp[lane] = (int)(v & 8191ull);
    } else {
      bool v1 = ((u32)(lane + 64) < cnt);
      u32 m1 = v1 ? (u32)ssurv[qq][lane + 64] : 0u;
      double s1 = ddist(Qx, Qy, Qz, Qd2, X[m1 * 3], X[m1 * 3 + 1], X[m1 * 3 + 2]);
      u64 k1 = v1 ? ((sortable64(s1) & 0xFFFFFFFFFFFFE000ull) | (u64)m1) : ~0ull;
      u32 selm = 0;
      for (int r = 0; r < KK; ++r) {
        u64 mk = (k0 < k1) ? k0 : k1;
#pragma unroll
        for (int j = 32; j > 0; j >>= 1) {
          u64 p = __shfl_xor(mk, j);
          if (p < mk) mk = p;
        }
        if (k0 == mk) k0 = ~0ull;
        else if (k1 == mk) k1 = ~0ull;
        if (lane == r) selm = (u32)(mk & 8191ull);
      }
      if (lane < KK) outp[lane] = (int)selm;
    }
  }
}

// ---------- K3: gather + max + relu + transpose-write ----------
__global__ __launch_bounds__(256) void k_gather(
    const u32* __restrict__ ucat, const u32* __restrict__ vcat,
    const int* __restrict__ knn, float* __restrict__ out) {
  __shared__ float tr[64 * 258];

  const int t = threadIdx.x;
  const int b = blockIdx.x >> 7;
  const int n0 = (blockIdx.x & 127) << 6;
  const int w = t >> 6, lane = t & 63;
  const int which = w >> 1;
  const int lo = ((w & 1) << 6) | lane;

  for (int step = 0; step < 32; ++step) {
    int qq = step * 2 + which;
    int q = n0 + qq;
    const int* ip = knn + ((b << 13) + q) * KK;
    float a0 = -__builtin_inff(), a1 = -__builtin_inff();
#pragma unroll
    for (int k = 0; k < KK; ++k) {
      int p = ip[k];
      u32 d = vcat[(((b << 13) + p) << 7) + lo];
      a0 = fmaxf(a0, bflo(d));
      a1 = fmaxf(a1, bfhi(d));
    }
    u32 u = ucat[(((b << 13) + q) << 7) + lo];
    float r0 = fmaxf(bflo(u) + a0, 0.0f);
    float r1 = fmaxf(bfhi(u) + a1, 0.0f);
    *(float2*)&tr[qq * 258 + 2 * lo] = make_float2(r0, r1);
  }
  __syncthreads();

  float* ob = out + b * (256 * NN);
  for (int i = 0; i < 64; ++i) {
    int o = (w << 6) + i;
    ob[o * NN + n0 + lane] = tr[lane * 258 + o];
  }
}

// ---------- launch ----------
extern "C" void kernel_launch(void* const* d_in, const int* in_sizes, int n_in,
                              void* d_out, int out_size, void* d_ws, size_t ws_size,
                              hipStream_t stream) {
  const float* xyz = (const float*)d_in[0];
  const float* f   = (const float*)d_in[1];
  const float* Wg  = (const float*)d_in[2];
  const float* gg  = (const float*)d_in[3];
  const float* bg  = (const float*)d_in[4];
  const float* mg  = (const float*)d_in[5];
  const float* vg  = (const float*)d_in[6];
  const float* Wf  = (const float*)d_in[7];
  const float* gf  = (const float*)d_in[8];
  const float* bf_ = (const float*)d_in[9];
  const float* mf  = (const float*)d_in[10];
  const float* vf  = (const float*)d_in[11];

  char* ws = (char*)d_ws;
  u16*   Wt     = (u16*)ws;                               // 65536 B
  float* beta_f = (float*)(ws + 65536);
  float* Wgu    = (float*)(ws + 66048);
  float* Wgv    = (float*)(ws + 67584);
  float* beta_g = (float*)(ws + 69120);
  u32*   ucat   = (u32*)(ws + 69632);                     // 8 MB
  u32*   vcat   = (u32*)(ws + 69632 + 8388608);           // 8 MB
  int*   knn    = (int*)(ws + 69632 + 2 * 8388608);       // 1.4 MB
  float* out    = (float*)d_out;

  if (ws_size < (size_t)(69632 + 2 * 8388608 + 16384 * KK * 4)) return;

  k_prep<<<dim3(128), dim3(256), 0, stream>>>(Wf, gf, bf_, mf, vf, Wg, gg, bg, mg, vg,
                                              Wt, beta_f, Wgu, Wgv, beta_g);
  k_geo<<<dim3(4096), dim3(256), 0, stream>>>(xyz, Wgu, Wgv, beta_g, ucat, vcat);
  k_feat<<<dim3(256), dim3(256), 0, stream>>>(f, (const u32*)Wt, beta_f, ucat, vcat);
  k_knn<<<dim3(2048), dim3(256), 0, stream>>>(xyz, knn);
  k_gather<<<dim3(256), dim3(256), 0, stream>>>(ucat, vcat, knn, out);
}

// Round 5
// 184.499 us; speedup vs baseline: 1.8510x; 1.4734x over previous
//
#include <hip/hip_runtime.h>

typedef unsigned int u32;
typedef unsigned long long u64;
typedef unsigned short u16;

#define DEV __device__ __forceinline__

// ---------- helpers ----------
DEV u16 f2bf(float x) {                      // fp32 -> bf16 RNE
  u32 u = __float_as_uint(x);
  u32 r = u + 0x7fffu + ((u >> 16) & 1u);
  return (u16)(r >> 16);
}
DEV float bflo(u32 d) { return __uint_as_float(d << 16); }
DEV float bfhi(u32 d) { return __uint_as_float(d & 0xffff0000u); }
DEV u64 sortable64(double f) {               // monotonic f64 -> u64
  long long b = __double_as_longlong(f);
  return (u64)b ^ (u64)((b >> 63) | (long long)0x8000000000000000ll);
}
// fp64 exact-selection distance (float products are exact in f64)
DEV double ddist(double qx, double qy, double qz, double qd2,
                 float mxf, float myf, float mzf) {
  double cx = (double)mxf, cy = (double)myf, cz = (double)mzf;
  double cd2 = cx * cx + cy * cy + cz * cz;
  double dot = cx * qx + cy * qy + cz * qz;
  return (qd2 + cd2) - 2.0 * dot;
}

#define NB 2
#define NN 8192
#define NC 128
#define KK 21
// screening metric: st = cd2 - 2*dot (qd2 dropped — per-query constant shift).
// fp32 error vs fp64 <= ~2e-4 on these operand scales; MARGIN covers it so the
// fp64 top-21 set provably survives fp32 screening.
#define MARGIN 1e-3f
#define CT 2048                              // candidate tile size

// ---------- K0: fold BN into weights ----------
__global__ __launch_bounds__(256) void k_prep(
    const float* __restrict__ Wf, const float* __restrict__ gf, const float* __restrict__ bf_,
    const float* __restrict__ mf, const float* __restrict__ vf,
    const float* __restrict__ Wg, const float* __restrict__ gg, const float* __restrict__ bg,
    const float* __restrict__ mg, const float* __restrict__ vg,
    u16* __restrict__ Wt, float* __restrict__ beta_f,
    float* __restrict__ Wgu, float* __restrict__ Wgv, float* __restrict__ beta_g) {
  int g = blockIdx.x * 256 + threadIdx.x;     // 0..32767
  int c = g >> 8, o = g & 255;
  float val;
  if (o < 128) {
    float inv = gf[o] / sqrtf(vf[o] + 1e-5f);
    val = inv * (Wf[o * 256 + c] - Wf[o * 256 + c + 128]);
  } else {
    int o2 = o - 128;
    float inv = gf[o2] / sqrtf(vf[o2] + 1e-5f);
    val = inv * Wf[o2 * 256 + c + 128];
  }
  Wt[c * 256 + o] = f2bf(val);
  if (g < 128) {
    float inv = gf[g] / sqrtf(vf[g] + 1e-5f);
    beta_f[g] = bf_[g] - mf[g] * inv;
  } else if (g < 256) {
    int oo = g - 128;
    float invg = gg[oo] / sqrtf(vg[oo] + 1e-5f);
#pragma unroll
    for (int d = 0; d < 3; ++d) {
      Wgu[oo * 3 + d] = invg * (Wg[oo * 6 + d] - Wg[oo * 6 + 3 + d]);
      Wgv[oo * 3 + d] = invg * Wg[oo * 6 + 3 + d];
    }
    beta_g[oo] = bg[oo] - mg[oo] * invg;
  }
}

// ---------- K1geo ----------
__global__ __launch_bounds__(256) void k_geo(
    const float* __restrict__ xyz, const float* __restrict__ Wgu, const float* __restrict__ Wgv,
    const float* __restrict__ beta_g, u32* __restrict__ ucat, u32* __restrict__ vcat) {
  int g = blockIdx.x * 256 + threadIdx.x;     // < 16384*64
  int p = g >> 6, oc = g & 63;
  const float* xp = xyz + p * 3;
  float X = xp[0], Y = xp[1], Z = xp[2];
  u32 du = 0, dv = 0;
#pragma unroll
  for (int h = 0; h < 2; ++h) {
    int o = oc * 2 + h;
    float ug = X * Wgu[o * 3] + Y * Wgu[o * 3 + 1] + Z * Wgu[o * 3 + 2] + beta_g[o];
    float vv = X * Wgv[o * 3] + Y * Wgv[o * 3 + 1] + Z * Wgv[o * 3 + 2];
    du |= (u32)f2bf(ug) << (16 * h);
    dv |= (u32)f2bf(vv) << (16 * h);
  }
  ucat[p * 128 + oc] = du;
  vcat[p * 128 + oc] = dv;
}

// ---------- K1f: feat branch GEMM, u/v-half split ----------
// Was 256 blocks @ 98.8KB LDS -> 1 block/CU (12.5% occupancy). Now each block
// does one 128-output half (H=0: u-weights, H=1: v-weights) of 64 points:
// sW 32KB + sF 34.8KB = 67.5KB -> 2 blocks/CU, 512 blocks. Same total FMA,
// same per-acc summation order (bit-identical outputs).
__global__ __launch_bounds__(256) void k_feat(
    const float* __restrict__ f, const u32* __restrict__ Wt32, const float* __restrict__ beta_f,
    u32* __restrict__ ucat, u32* __restrict__ vcat) {
  __shared__ u32 sW[128 * 64];                // this half's folded W (bf16 pairs)
  __shared__ float sF[128][68];

  const int t = threadIdx.x;
  const int blk = blockIdx.x;                 // 0..511
  const int H = blk & 1;                      // 0: u-half, 1: v-half
  const int b = blk >> 8;
  const int n0 = ((blk >> 1) & 127) << 6;
  const int boff = b * (NC * NN);

#pragma unroll
  for (int k = 0; k < 32; ++k) {
    int i = t + (k << 8);                     // 0..8191
    sW[i] = Wt32[((i >> 6) << 7) + (H << 6) + (i & 63)];
  }
#pragma unroll
  for (int k = 0; k < 32; ++k) {
    int i = t + (k << 8);
    int c = i >> 6, col = i & 63;
    sF[c][col] = f[boff + c * NN + n0 + col];
  }
  __syncthreads();

  const int w = t >> 6, lane = t & 63;
  const int og = lane >> 4, pg = lane & 15;
  const int o0 = (w << 5) + (og << 3);        // local channel 0..120 (step 8)
  const int p0 = pg << 2;                     // point 0..60 (step 4)

  float acc[8][4];
#pragma unroll
  for (int a = 0; a < 8; ++a)
#pragma unroll
    for (int p = 0; p < 4; ++p) acc[a][p] = 0.0f;

  for (int c = 0; c < 128; ++c) {
    float4 fa = *(const float4*)&sF[c][p0];
    uint4 wr = *(const uint4*)&sW[(c << 6) + (o0 >> 1)];
    float wv[8] = {bflo(wr.x), bfhi(wr.x), bflo(wr.y), bfhi(wr.y),
                   bflo(wr.z), bfhi(wr.z), bflo(wr.w), bfhi(wr.w)};
    float fv[4] = {fa.x, fa.y, fa.z, fa.w};
#pragma unroll
    for (int a = 0; a < 8; ++a)
#pragma unroll
      for (int p = 0; p < 4; ++p) acc[a][p] = __builtin_fmaf(wv[a], fv[p], acc[a][p]);
  }

  float bet[8];
#pragma unroll
  for (int a = 0; a < 8; ++a) bet[a] = (H == 0) ? beta_f[o0 + a] : 0.0f;
  u32* dstbase = (H == 0) ? ucat : vcat;
#pragma unroll
  for (int p = 0; p < 4; ++p) {
    int pt = (b << 13) + n0 + p0 + p;
    u32 d0 = (u32)f2bf(acc[0][p] + bet[0]) | ((u32)f2bf(acc[1][p] + bet[1]) << 16);
    u32 d1 = (u32)f2bf(acc[2][p] + bet[2]) | ((u32)f2bf(acc[3][p] + bet[3]) << 16);
    u32 d2 = (u32)f2bf(acc[4][p] + bet[4]) | ((u32)f2bf(acc[5][p] + bet[5]) << 16);
    u32 d3 = (u32)f2bf(acc[6][p] + bet[6]) | ((u32)f2bf(acc[7][p] + bet[7]) << 16);
    *(uint4*)&dstbase[pt * 128 + 64 + (o0 >> 1)] = make_uint4(d0, d1, d2, d3);
  }
}

// ---------- K2: exact KNN (k=21) — r0 configuration (measured 63 us) ----------
// Candidate-tiled, 16 queries/block, 4 q/wave, AoS float4 tiles. r1-r4 variants
// (SoA split-candidate structures) all regressed: 2x staging traffic + 4x
// barrier crossings outweigh any LDS-reuse gain, and launch_bounds min-waves
// args trigger hipcc's 256/min_waves VGPR budget -> scratch spill.
__global__ __launch_bounds__(256, 4) void k_knn(const float* __restrict__ xyz,
                                                int* __restrict__ knn) {
  __shared__ float4 sc[CT];                   // (x,y,z,d2) per candidate — 32 KB
  __shared__ u16 ssurv[16][128];              // 4 KB
  __shared__ u32 scnt[16];

  const int t = threadIdx.x;
  const int blk = blockIdx.x;                 // 0..1023
  const int b = blk >> 9;                     // 512 blocks per batch
  const int n0 = (blk & 511) << 4;            // 16 queries per block
  const float* X = xyz + b * (NN * 3);

  if (t < 16) scnt[t] = 0u;

  const int w = t >> 6, lane = t & 63;

  // query coords (4 queries per wave); fold -2x for the fma chain
  float mx[4], my[4], mz[4];
#pragma unroll
  for (int i = 0; i < 4; ++i) {
    int q = n0 + (w << 2) + i;
    mx[i] = -2.0f * X[q * 3];
    my[i] = -2.0f * X[q * 3 + 1];
    mz[i] = -2.0f * X[q * 3 + 2];
  }

  // ---- pass A: per-lane running min of st = cd2 - 2*dot ----
  float mn[4];
#pragma unroll
  for (int i = 0; i < 4; ++i) mn[i] = __builtin_inff();

  for (int ct = 0; ct < NN / CT; ++ct) {
    __syncthreads();                          // guard tile buffer reuse
    const float* Xt = X + ct * (CT * 3);
#pragma unroll
    for (int k = 0; k < 8; ++k) {
      int c = (k << 8) + t;
      float x = Xt[c * 3], y = Xt[c * 3 + 1], z = Xt[c * 3 + 2];
      float d2 = __builtin_fmaf(x, x, __builtin_fmaf(y, y, z * z));
      sc[c] = make_float4(x, y, z, d2);
    }
    __syncthreads();
#pragma unroll 4
    for (int cc = 0; cc < CT; cc += 64) {
      float4 C = sc[cc + lane];
#pragma unroll
      for (int i = 0; i < 4; ++i) {
        float s = __builtin_fmaf(C.x, mx[i],
                  __builtin_fmaf(C.y, my[i],
                  __builtin_fmaf(C.z, mz[i], C.w)));
        mn[i] = fminf(mn[i], s);
      }
    }
  }

  // ---- threshold: 21st smallest of 64 disjoint-subset lane minima ----
  // (any 21 of the minima witness 21 distinct candidates => upper bound on d21)
  float thr[4];
#pragma unroll
  for (int i = 0; i < 4; ++i) {
    float v = mn[i];
#pragma unroll
    for (int k = 2; k <= 64; k <<= 1) {
#pragma unroll
      for (int j = k >> 1; j > 0; j >>= 1) {
        float p = __shfl_xor(v, j);
        bool takeMin = (((lane & k) == 0) == ((lane & j) == 0));
        v = takeMin ? fminf(v, p) : fmaxf(v, p);
      }
    }
    thr[i] = __shfl(v, 20) + MARGIN;
  }

  // ---- pass B: compact survivors ----
  for (int ct = 0; ct < NN / CT; ++ct) {
    __syncthreads();
    const float* Xt = X + ct * (CT * 3);
#pragma unroll
    for (int k = 0; k < 8; ++k) {
      int c = (k << 8) + t;
      float x = Xt[c * 3], y = Xt[c * 3 + 1], z = Xt[c * 3 + 2];
      float d2 = __builtin_fmaf(x, x, __builtin_fmaf(y, y, z * z));
      sc[c] = make_float4(x, y, z, d2);
    }
    __syncthreads();
    int mbase = ct * CT + lane;
#pragma unroll 4
    for (int cc = 0; cc < CT; cc += 64) {
      float4 C = sc[cc + lane];
#pragma unroll
      for (int i = 0; i < 4; ++i) {
        float s = __builtin_fmaf(C.x, mx[i],
                  __builtin_fmaf(C.y, my[i],
                  __builtin_fmaf(C.z, mz[i], C.w)));
        if (s <= thr[i]) {
          int qq = (w << 2) + i;
          u32 slot = atomicAdd(&scnt[qq], 1u);
          if (slot < 128u) ssurv[qq][slot] = (u16)(mbase + cc);
        }
      }
    }
  }
  __syncthreads();

  // ---- selection: exact top-21 by fp64 (dist, idx) ----
#pragma unroll 1
  for (int i = 0; i < 4; ++i) {
    const int qq = (w << 2) + i;
    const int q = n0 + qq;
    double Qx = (double)X[q * 3], Qy = (double)X[q * 3 + 1], Qz = (double)X[q * 3 + 2];
    double Qd2 = Qx * Qx + Qy * Qy + Qz * Qz;
    u32 cnt = scnt[qq];
    int* outp = knn + ((b << 13) + q) * KK;

    bool v0 = ((u32)lane < cnt);
    u32 m0 = v0 ? (u32)ssurv[qq][lane] : 0u;
    double s0 = ddist(Qx, Qy, Qz, Qd2, X[m0 * 3], X[m0 * 3 + 1], X[m0 * 3 + 2]);
    // key: fp64-sortable, low 13 bits replaced by idx (lowest-index tie-break)
    u64 k0 = v0 ? ((sortable64(s0) & 0xFFFFFFFFFFFFE000ull) | (u64)m0) : ~0ull;

    if (cnt <= 64u) {
      u64 v = k0;
#pragma unroll
      for (int k = 2; k <= 64; k <<= 1) {
#pragma unroll
        for (int j = k >> 1; j > 0; j >>= 1) {
          u64 p = __shfl_xor(v, j);
          bool takeMin = (((lane & k) == 0) == ((lane & j) == 0));
          bool pl = p < v;
          u64 mnv = pl ? p : v;
          u64 mxv = pl ? v : p;
          v = takeMin ? mnv : mxv;
        }
      }
      if (lane < KK) outp[lane] = (int)(v & 8191ull);
    } else {
      bool v1 = ((u32)(lane + 64) < cnt);
      u32 m1 = v1 ? (u32)ssurv[qq][lane + 64] : 0u;
      double s1 = ddist(Qx, Qy, Qz, Qd2, X[m1 * 3], X[m1 * 3 + 1], X[m1 * 3 + 2]);
      u64 k1 = v1 ? ((sortable64(s1) & 0xFFFFFFFFFFFFE000ull) | (u64)m1) : ~0ull;
      u32 selm = 0;
      for (int r = 0; r < KK; ++r) {
        u64 mk = (k0 < k1) ? k0 : k1;
#pragma unroll
        for (int j = 32; j > 0; j >>= 1) {
          u64 p = __shfl_xor(mk, j);
          if (p < mk) mk = p;
        }
        if (k0 == mk) k0 = ~0ull;
        else if (k1 == mk) k1 = ~0ull;
        if (lane == r) selm = (u32)(mk & 8191ull);
      }
      if (lane < KK) outp[lane] = (int)selm;
    }
  }
}

// ---------- K3: gather + max + relu + transpose-write, channel-half split ----------
// Was 256 blocks @ 66KB LDS -> 1 block/CU. Now each block handles 64 of the
// 128 u32 channel-columns (H half): tr 33.3KB -> 4 blocks/CU LDS-wise, 512
// blocks (2/CU). Each wave owns query residue qq%4==w; transpose via
// stride-129 LDS (conflict-free on the read side; r0/r1 stored in split
// column halves so both stores are stride-1).
__global__ __launch_bounds__(256) void k_gather(
    const u32* __restrict__ ucat, const u32* __restrict__ vcat,
    const int* __restrict__ knn, float* __restrict__ out) {
  __shared__ float tr[64 * 129];

  const int t = threadIdx.x;
  const int blk = blockIdx.x;                 // 0..511
  const int H = blk & 1;                      // channel-column half
  const int b = blk >> 8;
  const int n0 = ((blk >> 1) & 127) << 6;
  const int w = t >> 6, lane = t & 63;
  const int lo = (H << 6) | lane;             // global u32 column 0..127

  for (int step = 0; step < 16; ++step) {
    int qq = step * 4 + w;
    int q = n0 + qq;
    const int* ip = knn + ((b << 13) + q) * KK;
    float a0 = -__builtin_inff(), a1 = -__builtin_inff();
#pragma unroll
    for (int k = 0; k < KK; ++k) {
      int p = ip[k];
      u32 d = vcat[(((b << 13) + p) << 7) + lo];
      a0 = fmaxf(a0, bflo(d));
      a1 = fmaxf(a1, bfhi(d));
    }
    u32 u = ucat[(((b << 13) + q) << 7) + lo];
    float r0 = fmaxf(bflo(u) + a0, 0.0f);     // local even channel 2*lane
    float r1 = fmaxf(bfhi(u) + a1, 0.0f);     // local odd channel 2*lane+1
    tr[qq * 129 + lane] = r0;                 // cols 0..63  <-> even channels
    tr[qq * 129 + 64 + lane] = r1;            // cols 64..127 <-> odd channels
  }
  __syncthreads();

  float* ob = out + b * (256 * NN) + (H << 7) * NN;
  for (int i = 0; i < 32; ++i) {
    int o = (w << 5) + i;                     // local channel 0..127
    int col = ((o & 1) << 6) + (o >> 1);
    ob[o * NN + n0 + lane] = tr[lane * 129 + col];
  }
}

// ---------- launch ----------
extern "C" void kernel_launch(void* const* d_in, const int* in_sizes, int n_in,
                              void* d_out, int out_size, void* d_ws, size_t ws_size,
                              hipStream_t stream) {
  const float* xyz = (const float*)d_in[0];
  const float* f   = (const float*)d_in[1];
  const float* Wg  = (const float*)d_in[2];
  const float* gg  = (const float*)d_in[3];
  const float* bg  = (const float*)d_in[4];
  const float* mg  = (const float*)d_in[5];
  const float* vg  = (const float*)d_in[6];
  const float* Wf  = (const float*)d_in[7];
  const float* gf  = (const float*)d_in[8];
  const float* bf_ = (const float*)d_in[9];
  const float* mf  = (const float*)d_in[10];
  const float* vf  = (const float*)d_in[11];

  char* ws = (char*)d_ws;
  u16*   Wt     = (u16*)ws;                               // 65536 B
  float* beta_f = (float*)(ws + 65536);
  float* Wgu    = (float*)(ws + 66048);
  float* Wgv    = (float*)(ws + 67584);
  float* beta_g = (float*)(ws + 69120);
  u32*   ucat   = (u32*)(ws + 69632);                     // 8 MB
  u32*   vcat   = (u32*)(ws + 69632 + 8388608);           // 8 MB
  int*   knn    = (int*)(ws + 69632 + 2 * 8388608);       // 1.4 MB
  float* out    = (float*)d_out;

  if (ws_size < (size_t)(69632 + 2 * 8388608 + 16384 * KK * 4)) return;

  k_prep<<<dim3(128), dim3(256), 0, stream>>>(Wf, gf, bf_, mf, vf, Wg, gg, bg, mg, vg,
                                              Wt, beta_f, Wgu, Wgv, beta_g);
  k_geo<<<dim3(4096), dim3(256), 0, stream>>>(xyz, Wgu, Wgv, beta_g, ucat, vcat);
  k_feat<<<dim3(512), dim3(256), 0, stream>>>(f, (const u32*)Wt, beta_f, ucat, vcat);
  k_knn<<<dim3(1024), dim3(256), 0, stream>>>(xyz, knn);
  k_gather<<<dim3(512), dim3(256), 0, stream>>>(ucat, vcat, knn, out);
}